// Round 2
// baseline (1426.458 us; speedup 1.0000x reference)
//
#include <hip/hip_runtime.h>
#include <hip/hip_fp16.h>
#include <stdint.h>

// Problem constants (fixed by reference)
#define HID   2048
#define FFN   2816
#define FFN2  5632
#define NE    8
#define NTOK  4096
#define NPAIR 8192
#define BM    256
#define PADMAX (NPAIR + NE * BM)   // 10240 padded rows max
#define MT_MAX (PADMAX / BM)       // 40 M-tiles max
#define KT1   (HID / 32)           // 64 K-steps for GEMM1
#define KT2   (FFN / 32)           // 88 K-steps for GEMM2
#define NT1   (FFN / 64)           // 44 N-tiles GEMM1 (dual-half)
#define NT2   (HID / 64)           // 32 N-tiles GEMM2

typedef _Float16 f16;
typedef f16   f16x8 __attribute__((ext_vector_type(8)));
typedef float f32x4 __attribute__((ext_vector_type(4)));

// XOR swizzle within a [rows][32] fp16 tile (row stride 64B). Bijective:
// bits7+ give row>>1; bit6 = (row&1)^((row>>2)&1) -> row&1 recoverable;
// bits0-5 = kbyte ^ ((row&3)<<4). Fragment reads land 2-way on banks (free).
#define SWZ(row, kbyte) ((((row) * 64) + (kbyte)) ^ (((row) & 7) << 4))

// Workspace layout (bytes). Requires ws_size >= ~167 MB.
#define WS_META   0
#define WS_PAIR   4096
#define WS_A      65536
#define A_BYTES   ((size_t)MT_MAX * KT1 * 16384)   // 41,943,040
#define WS_ACT    (WS_A + A_BYTES)
#define ACT_BYTES ((size_t)MT_MAX * KT2 * 16384)   // 57,671,680
#define WS_YP     (WS_ACT + ACT_BYTES)
#define YP_BYTES  ((size_t)NPAIR * HID * 4)        // 67,108,864
#define WS_NEED   (WS_YP + YP_BYTES)               // ~166.8 MB

__device__ __forceinline__ void load_lds16(const void* g, void* l) {
  __builtin_amdgcn_global_load_lds(
      (const __attribute__((address_space(1))) unsigned int*)g,
      (__attribute__((address_space(3))) unsigned int*)l, 16, 0, 0);
}

// meta ints: [0:8) counts, [8:16) cursors, [16:25) paddedOff,
//            [32:72) tileExpert, [72] nTiles, [73] nRows
__global__ void moe_init(int* __restrict__ meta, int* __restrict__ pairIdx) {
  int i = blockIdx.x * 256 + threadIdx.x;
  if (i < 16) meta[i] = 0;
  if (i < PADMAX) pairIdx[i] = -1;
}

__global__ void moe_count(const int* __restrict__ te, int* __restrict__ meta) {
  int i = blockIdx.x * 256 + threadIdx.x;
  if (i < NPAIR) atomicAdd(&meta[te[i] & 7], 1);
}

__global__ void moe_scan(int* __restrict__ meta) {
  if (threadIdx.x != 0) return;
  int off = 0, tiles = 0;
  for (int e = 0; e < NE; ++e) {
    meta[16 + e] = off;
    int c = meta[e];
    int t = (c + BM - 1) / BM;
    for (int i = 0; i < t; ++i) meta[32 + tiles + i] = e;
    tiles += t;
    off += t * BM;
  }
  meta[16 + NE] = off;
  meta[72] = tiles;
  meta[73] = off;
}

__global__ void moe_scatter(const int* __restrict__ te, int* __restrict__ meta,
                            int* __restrict__ pairIdx) {
  int i = blockIdx.x * 256 + threadIdx.x;
  if (i < NPAIR) {
    int e = te[i] & 7;
    int pos = meta[16 + e] + atomicAdd(&meta[8 + e], 1);
    pairIdx[pos] = i;
  }
}

// Gather token rows (fp32 -> fp16) into blocked+swizzled A: [mt][kt][256][32].
// Reads coalesced (8KB contiguous per block); writes 16B/lane swizzle-scatter.
__global__ void moe_gather(const float* __restrict__ x, const int* __restrict__ pairIdx,
                           const int* __restrict__ meta, f16* __restrict__ A) {
  int r = blockIdx.x;
  if (r >= meta[73]) return;
  int t = threadIdx.x;
  int p = pairIdx[r];
  int rl = r & (BM - 1), mt = r >> 8;
  int kt = t >> 2, kk = (t & 3) * 8;
  size_t byte = ((size_t)(mt * KT1 + kt)) * 16384 + (size_t)SWZ(rl, kk * 2);
  f16x8 v;
  if (p >= 0) {
    const float* src = x + ((size_t)(p >> 1)) * HID + (t * 8);  // token = p>>1
#pragma unroll
    for (int j = 0; j < 8; ++j) v[j] = (f16)src[j];
  } else {
#pragma unroll
    for (int j = 0; j < 8; ++j) v[j] = (f16)0.f;
  }
  *(f16x8*)((char*)A + byte) = v;
}

// Grouped GEMM. HALVES==2: fc1 + fused SwiGLU -> ActOut (blocked+swizzled fp16).
// HALVES==1: fc2 -> Yp[p][col] = ew[p] * y (fp32).
// Block: 256 thr = 4 waves, tile BM=256 x BN=64 (x HALVES), BK=32.
template <int HALVES, int KSTEPS, int NTILES, int LDB>
__global__ __launch_bounds__(256, 2) void moe_gemm(
    const f16* __restrict__ A, const float* __restrict__ B,
    const float* __restrict__ bias, const int* __restrict__ meta,
    const int* __restrict__ pairIdx, const float* __restrict__ ew,
    f16* __restrict__ ActOut, float* __restrict__ Yp) {
  const int nActive = meta[72];
  int hw = blockIdx.x;
  // bijective XCD chunk map (grid divisible by 8); mt fastest -> same-nt
  // (same weight slice) blocks co-resident on one XCD for L2 reuse (T1).
  int cpx = (MT_MAX * NTILES) >> 3;
  int lg = (hw & 7) * cpx + (hw >> 3);
  int mt = lg % MT_MAX;
  int nt = lg / MT_MAX;
  if (mt >= nActive) return;  // block-uniform exit (no barrier divergence)
  int e = meta[32 + mt];
  int n0 = nt * 64;
  int tid = threadIdx.x, w = tid >> 6, ln = tid & 63;
  int l15 = ln & 15, lq = ln >> 4;

  __shared__ f16 Al[BM * 32];            // 16 KB, one pre-swizzled A K-tile
  __shared__ f16 Bl[HALVES * 64 * 32];   // 4/8 KB, transposed [n][k] swizzled

  f32x4 acc[HALVES][4][4] = {};

  const float* Bp = B + (size_t)e * (KSTEPS * 32) * LDB;
  const char* Ablk = (const char*)A + (size_t)mt * KSTEPS * 16384;

  int sn = tid & 63;    // staging: n within tile
  int sk8 = tid >> 6;   // staging: k-group (8 k-rows per wave)

  for (int ks = 0; ks < KSTEPS; ++ks) {
    // ---- stage A: 16 KB linear gload_lds copy (layout pre-swizzled in ws)
    const char* asrc = Ablk + (size_t)ks * 16384;
#pragma unroll
    for (int i = 0; i < 4; ++i) {
      int off = w * 4096 + i * 1024;
      load_lds16(asrc + off + ln * 16, (char*)Al + off);
    }
    // ---- stage B: coalesced fp32 row loads -> fp16 -> swizzled ds_write_b128
#pragma unroll
    for (int h = 0; h < HALVES; ++h) {
      const float* bsrc = Bp + (size_t)(ks * 32 + sk8 * 8) * LDB + (n0 + h * FFN + sn);
      float tv[8];
#pragma unroll
      for (int j = 0; j < 8; ++j) tv[j] = bsrc[(size_t)j * LDB];
      f16x8 bv;
#pragma unroll
      for (int j = 0; j < 8; ++j) bv[j] = (f16)tv[j];
      *(f16x8*)((char*)Bl + (h * 4096 + SWZ(sn, sk8 * 16))) = bv;
    }
    __syncthreads();
    // ---- fragments + MFMA (A: m=l&15,k=(l>>4)*8+j ; B: n=l&15 same k)
    f16x8 af[4];
#pragma unroll
    for (int mf = 0; mf < 4; ++mf) {
      int row = w * 64 + mf * 16 + l15;
      af[mf] = *(const f16x8*)((const char*)Al + SWZ(row, lq * 16));
    }
#pragma unroll
    for (int h = 0; h < HALVES; ++h) {
#pragma unroll
      for (int nf = 0; nf < 4; ++nf) {
        int n = nf * 16 + l15;
        f16x8 bf = *(const f16x8*)((const char*)Bl + (h * 4096 + SWZ(n, lq * 16)));
#pragma unroll
        for (int mf = 0; mf < 4; ++mf)
          acc[h][mf][nf] =
              __builtin_amdgcn_mfma_f32_16x16x32_f16(af[mf], bf, acc[h][mf][nf], 0, 0, 0);
      }
    }
    __syncthreads();
  }

  // D layout (m89-verified): col = l&15, row = (l>>4)*4 + r
  if constexpr (HALVES == 2) {
    float ba[4], bb[4];
#pragma unroll
    for (int nf = 0; nf < 4; ++nf) {
      int col = n0 + nf * 16 + l15;
      ba[nf] = bias[e * FFN2 + col];
      bb[nf] = bias[e * FFN2 + FFN + col];
    }
#pragma unroll
    for (int mf = 0; mf < 4; ++mf) {
      int rl = w * 64 + mf * 16 + lq * 4;
#pragma unroll
      for (int nf = 0; nf < 4; ++nf) {
        int ck = n0 + nf * 16 + l15;  // activation col = k-index for GEMM2
        size_t base = ((size_t)(mt * KT2 + (ck >> 5))) * 16384;
#pragma unroll
        for (int r = 0; r < 4; ++r) {
          float a = acc[0][mf][nf][r] + ba[nf];
          float b = acc[1][mf][nf][r] + bb[nf];
          float s = (a / (1.f + __expf(-a))) * b;  // silu(a)*b
          *(f16*)((char*)ActOut + base + SWZ(rl + r, (ck & 31) * 2)) = (f16)s;
        }
      }
    }
  } else {
    float bn[4];
#pragma unroll
    for (int nf = 0; nf < 4; ++nf) bn[nf] = bias[e * HID + n0 + nf * 16 + l15];
#pragma unroll
    for (int mf = 0; mf < 4; ++mf) {
#pragma unroll
      for (int r = 0; r < 4; ++r) {
        int prow = mt * BM + w * 64 + mf * 16 + lq * 4 + r;
        int p = pairIdx[prow];
        if (p >= 0) {
          float wgt = ew[p];
#pragma unroll
          for (int nf = 0; nf < 4; ++nf)
            Yp[(size_t)p * HID + (n0 + nf * 16 + l15)] =
                wgt * (acc[0][mf][nf][r] + bn[nf]);
        }
      }
    }
  }
}

__global__ void moe_combine(const float* __restrict__ Yp, float* __restrict__ out) {
  int i = blockIdx.x * 256 + threadIdx.x;  // exactly NTOK*512 threads
  int n = i >> 9, c = i & 511;
  const f32x4* y = (const f32x4*)Yp;
  f32x4 v = y[((size_t)(2 * n)) * 512 + c] + y[((size_t)(2 * n + 1)) * 512 + c];
  ((f32x4*)out)[i] = v;
}

extern "C" void kernel_launch(void* const* d_in, const int* in_sizes, int n_in,
                              void* d_out, int out_size, void* d_ws, size_t ws_size,
                              hipStream_t stream) {
  const float* x  = (const float*)d_in[0];
  const float* ew = (const float*)d_in[1];
  const float* w1 = (const float*)d_in[2];
  const float* b1 = (const float*)d_in[3];
  const float* w2 = (const float*)d_in[4];
  const float* b2 = (const float*)d_in[5];
  const int*   te = (const int*)d_in[6];
  float* out = (float*)d_out;
  char* ws = (char*)d_ws;
  if (ws_size < WS_NEED) return;  // need ~167 MB scratch

  int* meta     = (int*)(ws + WS_META);
  int* pairIdx  = (int*)(ws + WS_PAIR);
  f16* A        = (f16*)(ws + WS_A);
  f16* Act      = (f16*)(ws + WS_ACT);
  float* Yp     = (float*)(ws + WS_YP);

  moe_init<<<PADMAX / 256, 256, 0, stream>>>(meta, pairIdx);
  moe_count<<<NPAIR / 256, 256, 0, stream>>>(te, meta);
  moe_scan<<<1, 64, 0, stream>>>(meta);
  moe_scatter<<<NPAIR / 256, 256, 0, stream>>>(te, meta, pairIdx);
  moe_gather<<<PADMAX, 256, 0, stream>>>(x, pairIdx, meta, A);
  moe_gemm<2, KT1, NT1, FFN2>
      <<<MT_MAX * NT1, 256, 0, stream>>>(A, w1, b1, meta, pairIdx, ew, Act, nullptr);
  moe_gemm<1, KT2, NT2, HID>
      <<<MT_MAX * NT2, 256, 0, stream>>>(Act, w2, b2, meta, pairIdx, ew, nullptr, Yp);
  moe_combine<<<(NTOK * 512) / 256, 256, 0, stream>>>(Yp, out);
}